// Round 3
// baseline (6860.906 us; speedup 1.0000x reference)
//
#include <hip/hip_runtime.h>
#include <hip/hip_bf16.h>
#include <float.h>
#include <math.h>

#define NCORP   500000
#define KDIM    256
#define BPAT    512
#define TM      128     // corpus rows per tile
#define TNP     64      // patients per block
#define TKK     32
#define TILES_TOTAL 3907            // ceil(500000/128)
#define NCHUNK  128
#define TILES_PER_CHUNK 31          // ceil(3907/128)
#define SC_LO  (-1.0009f)
#define SC_HI  ( 1.0009f)

// ---- d_out offsets (float elements) ----
#define O_FACT  0
#define O_TARG  512
#define O_CF    1024
#define O_PS    2048
#define O_PL    3072
#define O_SC    4096
#define O_IDX   8192
#define O_S     12288

// ---- workspace layout (float elements) ----
#define PET_OFF 0                    // peT [256][512]
#define CS_OFF  131072               // chunkScore [128][512][8]
#define CI_OFF  655360               // chunkIdx   [128][512][8] (int)
#define TI_OFF  1179648              // topIdx [512][8] (int)
#define SIN_OFF 1183744              // sharedIn [512][2176]
#define H1_OFF  2297856              // h1 [512][1024]
#define H2_OFF  2822144              // h2 [512][1024]
#define S_OFF   3346432              // s  [512][512]
#define INV_OFF 3608576              // invNorm [500000]

// ============ corpus inverse row norms: one wave per row ============
__global__ __launch_bounds__(256) void k_norms(const float* __restrict__ corpus,
                                               float* __restrict__ invNorm) {
    const int wave = threadIdx.x >> 6;
    const int lane = threadIdx.x & 63;
    const int row = blockIdx.x * 4 + wave;
    if (row >= NCORP) return;
    float4 v = *(const float4*)(corpus + (size_t)row * KDIM + lane * 4);
    float s = v.x * v.x + v.y * v.y + v.z * v.z + v.w * v.w;
#pragma unroll
    for (int off = 32; off > 0; off >>= 1) s += __shfl_xor(s, off);
    if (lane == 0) invNorm[row] = 1.0f / fmaxf(sqrtf(s), 1e-12f);
}

// ============ pe = normalize(pf @ W_pe + b_pe), stored transposed ============
__global__ __launch_bounds__(256) void k_pe(const float* __restrict__ pf,
                                            const float* __restrict__ W_pe,
                                            const float* __restrict__ b_pe,
                                            float* __restrict__ peT) {
    __shared__ float pfs[130];
    __shared__ float red[256];
    const int b = blockIdx.x, t = threadIdx.x;
    if (t < 130) pfs[t] = pf[b * 130 + t];
    __syncthreads();
    float acc = b_pe[t];
    for (int k = 0; k < 130; ++k) acc += pfs[k] * W_pe[k * 256 + t];
    red[t] = acc * acc;
    __syncthreads();
    for (int s = 128; s > 0; s >>= 1) {
        if (t < s) red[t] += red[t + s];
        __syncthreads();
    }
    float inv = 1.0f / fmaxf(sqrtf(red[0]), 1e-12f);
    peT[(size_t)t * BPAT + b] = acc * inv;
}

// ============ fused sim GEMM (fp32) + per-chunk top-8 ============
__global__ __launch_bounds__(256) void k_sim_topk(const float* __restrict__ corpus,
                                                  const float* __restrict__ peT,
                                                  const float* __restrict__ invNorm,
                                                  float* __restrict__ chunkScore,
                                                  int* __restrict__ chunkIdx) {
    __shared__ float At[TKK][TM + 4];     // transposed A tile
    __shared__ float Bt[TKK][TNP + 4];
    __shared__ float Ct[TM][TNP + 4];
    __shared__ float invn[TM];

    const int t = threadIdx.x;
    const int pg = blockIdx.x;            // 0..7 patient group (fastest -> L2/L3 reuse)
    const int chunk = blockIdx.y;         // 0..127
    const int pstart = pg * TNP;

    const int tm = t & 15;                // acc rows tm*8..+7
    const int tn = t >> 4;                // acc cols tn*4..+3

    const int lc = t & 7;                 // A staging: float4 col
    const int rb = t >> 3;                // A staging: base row (rows rb + 32p)
    const int c4 = t & 15;                // B staging
    const int r2 = t >> 4;

    float sc[8];
    int ix[8];
#pragma unroll
    for (int j = 0; j < 8; ++j) { sc[j] = -FLT_MAX; ix[j] = 0x7fffffff; }

    const int ti0 = chunk * TILES_PER_CHUNK;
    const int ti1 = min(ti0 + TILES_PER_CHUNK, TILES_TOTAL);

    for (int ti = ti0; ti < ti1; ++ti) {
        const int rowstart = ti * TM;
        float acc[8][4];
#pragma unroll
        for (int i = 0; i < 8; ++i)
#pragma unroll
            for (int j = 0; j < 4; ++j) acc[i][j] = 0.f;

        for (int kt = 0; kt < KDIM / TKK; ++kt) {
            __syncthreads();
#pragma unroll
            for (int p = 0; p < 4; ++p) {
                const int r = rb + 32 * p;
                const int grow = rowstart + r;
                float4 v = make_float4(0.f, 0.f, 0.f, 0.f);
                if (grow < NCORP)
                    v = *(const float4*)(corpus + (size_t)grow * KDIM + kt * TKK + lc * 4);
                At[lc * 4 + 0][r] = v.x;
                At[lc * 4 + 1][r] = v.y;
                At[lc * 4 + 2][r] = v.z;
                At[lc * 4 + 3][r] = v.w;
            }
#pragma unroll
            for (int i = 0; i < 2; ++i) {
                const int r = r2 + 16 * i;
                float4 v = *(const float4*)(peT + (size_t)(kt * TKK + r) * BPAT + pstart + c4 * 4);
                *(float4*)&Bt[r][c4 * 4] = v;
            }
            __syncthreads();
#pragma unroll
            for (int kk = 0; kk < TKK; ++kk) {
                float a[8], bv[4];
                *(float4*)&a[0] = *(const float4*)&At[kk][tm * 8];
                *(float4*)&a[4] = *(const float4*)&At[kk][tm * 8 + 4];
                *(float4*)&bv[0] = *(const float4*)&Bt[kk][tn * 4];
#pragma unroll
                for (int i = 0; i < 8; ++i)
#pragma unroll
                    for (int j = 0; j < 4; ++j) acc[i][j] += a[i] * bv[j];
            }
        }
        __syncthreads();
        if (t < TM) {
            const int g = rowstart + t;
            invn[t] = (g < NCORP) ? invNorm[g] : 0.f;
        }
        __syncthreads();
#pragma unroll
        for (int i = 0; i < 8; ++i) {
            const int r = tm * 8 + i;
            const float s = invn[r];
            float4 v = make_float4(acc[i][0] * s, acc[i][1] * s, acc[i][2] * s, acc[i][3] * s);
            *(float4*)&Ct[r][tn * 4] = v;
        }
        __syncthreads();
        if (t < TNP) {
            for (int r = 0; r < TM; ++r) {
                const int grow = rowstart + r;
                if (grow >= NCORP) break;
                const float v = Ct[r][t];
                // cosines are provably in [-1,1]; anything else is garbage -> drop
                if (v > sc[7] && v >= SC_LO && v <= SC_HI) {
                    sc[7] = v; ix[7] = grow;
#pragma unroll
                    for (int j = 7; j > 0; --j) {
                        if (sc[j] > sc[j - 1]) {
                            float ts = sc[j - 1]; sc[j - 1] = sc[j]; sc[j] = ts;
                            int tii = ix[j - 1]; ix[j - 1] = ix[j]; ix[j] = tii;
                        }
                    }
                }
            }
        }
    }
    if (t < TNP) {
        const int patient = pstart + t;
        const size_t base = ((size_t)chunk * BPAT + patient) * 8;
#pragma unroll
        for (int j = 0; j < 8; ++j) { chunkScore[base + j] = sc[j]; chunkIdx[base + j] = ix[j]; }
    }
}

// ============ merge per-chunk top-8 -> global top-8 (fp32 out) ============
__global__ __launch_bounds__(64) void k_merge(const float* __restrict__ chunkScore,
                                              const int* __restrict__ chunkIdx,
                                              int* __restrict__ topIdx,
                                              float* __restrict__ out) {
    __shared__ float ls[NCHUNK * 8];
    __shared__ int li[NCHUNK * 8];
    const int b = blockIdx.x, t = threadIdx.x;
    for (int e = t; e < NCHUNK * 8; e += 64) {
        const int c = e >> 3, j = e & 7;
        const size_t base = ((size_t)c * BPAT + b) * 8 + j;
        float v = chunkScore[base];
        if (!(v >= SC_LO && v <= SC_HI)) v = -FLT_MAX;   // drop garbage / NaN
        ls[e] = v;
        li[e] = chunkIdx[base];
    }
    __syncthreads();
    for (int sel = 0; sel < 8; ++sel) {
        float bs = -FLT_MAX; int bi = 0x7fffffff; int bslot = t * 16;
        for (int e = t * 16; e < t * 16 + 16; ++e) {
            const float v = ls[e]; const int id = li[e];
            if (v > bs || (v == bs && id < bi)) { bs = v; bi = id; bslot = e; }
        }
#pragma unroll
        for (int off = 32; off > 0; off >>= 1) {
            const float os = __shfl_xor(bs, off);
            const int oi = __shfl_xor(bi, off);
            const int osl = __shfl_xor(bslot, off);
            if (os > bs || (os == bs && oi < bi)) { bs = os; bi = oi; bslot = osl; }
        }
        if (t == 0) {
            ls[bslot] = -FLT_MAX;
            out[O_SC + b * 8 + sel] = bs;
            out[O_IDX + b * 8 + sel] = (float)bi;
            topIdx[b * 8 + sel] = bi;
        }
        __syncthreads();
    }
}

// ============ build shared_in = [confounders, retrieved] ============
__global__ __launch_bounds__(256) void k_gather(const float* __restrict__ conf,
                                                const float* __restrict__ corpus,
                                                const int* __restrict__ topIdx,
                                                float* __restrict__ sharedIn) {
    const int b = blockIdx.x, t = threadIdx.x;
    if (t < 128) sharedIn[(size_t)b * 2176 + t] = conf[b * 128 + t];
    for (int j = t; j < 2048; j += 256) {
        const int kk = j >> 8, e = j & 255;
        int gi = topIdx[b * 8 + kk];
        if (gi < 0 || gi >= NCORP) gi = 0;   // paranoia: never OOB
        sharedIn[(size_t)b * 2176 + 128 + j] = corpus[(size_t)gi * 256 + e];
    }
}

// ============ generic tiled fp32 GEMM: out = (relu?)(A[M,K]@W[K,N]+bias) ============
__global__ __launch_bounds__(256) void k_gemm(const float* __restrict__ A,
                                              const float* __restrict__ W,
                                              const float* __restrict__ bias,
                                              float* __restrict__ out,
                                              int K, int N, int relu) {
    __shared__ float At[16][64 + 4];
    __shared__ float Wt[16][64 + 4];
    const int t = threadIdx.x;
    const int colstart = blockIdx.x * 64;
    const int rowstart = blockIdx.y * 64;
    const int tm = t & 15, tn = t >> 4;
    float acc[4][4];
#pragma unroll
    for (int i = 0; i < 4; ++i)
#pragma unroll
        for (int j = 0; j < 4; ++j) acc[i][j] = 0.f;

    const int ac = t & 15, ar = t >> 4;        // A staging
    const int wc = t & 63, wr = t >> 6;        // W staging

    for (int kt = 0; kt < K / 16; ++kt) {
        __syncthreads();
#pragma unroll
        for (int i = 0; i < 4; ++i) {
            const int r = ar + 16 * i;
            At[ac][r] = A[(size_t)(rowstart + r) * K + kt * 16 + ac];
        }
#pragma unroll
        for (int i = 0; i < 4; ++i) {
            const int r = wr + 4 * i;
            Wt[r][wc] = W[(size_t)(kt * 16 + r) * N + colstart + wc];
        }
        __syncthreads();
#pragma unroll
        for (int kk = 0; kk < 16; ++kk) {
            float a[4], bv[4];
            *(float4*)a = *(const float4*)&At[kk][tm * 4];
            *(float4*)bv = *(const float4*)&Wt[kk][tn * 4];
#pragma unroll
            for (int i = 0; i < 4; ++i)
#pragma unroll
                for (int j = 0; j < 4; ++j) acc[i][j] += a[i] * bv[j];
        }
    }
    float b0 = bias[colstart + tn * 4 + 0];
    float b1 = bias[colstart + tn * 4 + 1];
    float b2 = bias[colstart + tn * 4 + 2];
    float b3 = bias[colstart + tn * 4 + 3];
#pragma unroll
    for (int i = 0; i < 4; ++i) {
        float4 v = make_float4(acc[i][0] + b0, acc[i][1] + b1, acc[i][2] + b2, acc[i][3] + b3);
        if (relu) {
            v.x = fmaxf(v.x, 0.f); v.y = fmaxf(v.y, 0.f);
            v.z = fmaxf(v.z, 0.f); v.w = fmaxf(v.w, 0.f);
        }
        *(float4*)(out + (size_t)(rowstart + tm * 4 + i) * N + colstart + tn * 4) = v;
    }
}

// ============ LayerNorm over 1024 cols, in place ============
__global__ __launch_bounds__(256) void k_ln(float* __restrict__ h,
                                            const float* __restrict__ g,
                                            const float* __restrict__ be) {
    __shared__ float red[256];
    const int b = blockIdx.x, t = threadIdx.x;
    float x[4];
    float s = 0.f, s2 = 0.f;
#pragma unroll
    for (int i = 0; i < 4; ++i) {
        x[i] = h[(size_t)b * 1024 + t + 256 * i];
        s += x[i]; s2 += x[i] * x[i];
    }
    red[t] = s; __syncthreads();
    for (int k = 128; k > 0; k >>= 1) { if (t < k) red[t] += red[t + k]; __syncthreads(); }
    const float mu = red[0] / 1024.f;
    __syncthreads();
    red[t] = s2; __syncthreads();
    for (int k = 128; k > 0; k >>= 1) { if (t < k) red[t] += red[t + k]; __syncthreads(); }
    const float var = red[0] / 1024.f - mu * mu;
    const float r = rsqrtf(var + 1e-5f);
#pragma unroll
    for (int i = 0; i < 4; ++i) {
        const int col = t + 256 * i;
        h[(size_t)b * 1024 + col] = (x[i] - mu) * r * g[col] + be[col];
    }
}

// ============ copy s to fp32 output ============
__global__ __launch_bounds__(256) void k_scast(const float* __restrict__ s,
                                               float* __restrict__ out) {
    for (int i = blockIdx.x * blockDim.x + threadIdx.x; i < BPAT * 512; i += gridDim.x * blockDim.x)
        out[O_S + i] = s[i];
}

// ============ fused heads ============
__device__ __forceinline__ float block_red(float v, float* red, int t) {
    red[t] = v; __syncthreads();
    for (int k = 128; k > 0; k >>= 1) { if (t < k) red[t] += red[t + k]; __syncthreads(); }
    const float r = red[0]; __syncthreads();
    return r;
}

__global__ __launch_bounds__(256) void k_heads(const float* __restrict__ s_mat,
                                               const float* __restrict__ treat,
                                               const float* __restrict__ Wt1, const float* __restrict__ bt1,
                                               const float* __restrict__ Wt2, const float* __restrict__ bt2,
                                               const float* __restrict__ Wo1, const float* __restrict__ bo1,
                                               const float* __restrict__ Wo2, const float* __restrict__ bo2,
                                               const float* __restrict__ Wg1, const float* __restrict__ bg1,
                                               const float* __restrict__ Wg2, const float* __restrict__ bg2,
                                               float* __restrict__ out) {
    __shared__ float srow[512];
    __shared__ float red[256];
    const int b = blockIdx.x, t = threadIdx.x;
    srow[t] = s_mat[(size_t)b * 512 + t];
    srow[t + 256] = s_mat[(size_t)b * 512 + 256 + t];
    __syncthreads();
    float at = bt1[t], ao = bo1[t], ag = bg1[t];
    for (int k = 0; k < 512; ++k) {
        const float sv = srow[k];
        at += sv * Wt1[k * 256 + t];
        ao += sv * Wo1[k * 256 + t];
        ag += sv * Wg1[k * 256 + t];
    }
    at = fmaxf(at, 0.f);
    const float tv0 = treat[b * 2 + 0], tv1 = treat[b * 2 + 1];
    const float ow0 = Wo1[512 * 256 + t], ow1 = Wo1[513 * 256 + t];
    const float gw0 = Wg1[512 * 256 + t], gw1 = Wg1[513 * 256 + t];
    const float fh = fmaxf(ao + tv0 * ow0 + tv1 * ow1, 0.f);
    const float c0 = fmaxf(ao + ow0, 0.f);
    const float c1 = fmaxf(ao + ow1, 0.f);
    const float gh = fmaxf(ag + tv0 * gw0 + tv1 * gw1, 0.f);
    const float wo2 = Wo2[t], wg2 = Wg2[t];
    const float pl0 = block_red(at * Wt2[t * 2 + 0], red, t);
    const float pl1 = block_red(at * Wt2[t * 2 + 1], red, t);
    const float fac = block_red(fh * wo2, red, t);
    const float cf0 = block_red(c0 * wo2, red, t);
    const float cf1 = block_red(c1 * wo2, red, t);
    const float tar = block_red(gh * wg2, red, t);
    if (t == 0) {
        const float l0 = pl0 + bt2[0], l1 = pl1 + bt2[1];
        const float f = fac + bo2[0], cc0 = cf0 + bo2[0], cc1 = cf1 + bo2[0];
        const float tg = tar + bg2[0];
        const float m = fmaxf(l0, l1);
        const float e0 = expf(l0 - m), e1 = expf(l1 - m);
        const float inv = 1.f / (e0 + e1);
        out[O_FACT + b] = f;
        out[O_TARG + b] = tg;
        out[O_CF + b * 2 + 0] = cc0;
        out[O_CF + b * 2 + 1] = cc1;
        out[O_PS + b * 2 + 0] = e0 * inv;
        out[O_PS + b * 2 + 1] = e1 * inv;
        out[O_PL + b * 2 + 0] = l0;
        out[O_PL + b * 2 + 1] = l1;
    }
}

extern "C" void kernel_launch(void* const* d_in, const int* in_sizes, int n_in,
                              void* d_out, int out_size, void* d_ws, size_t ws_size,
                              hipStream_t stream) {
    const float* pf     = (const float*)d_in[0];
    const float* treat  = (const float*)d_in[1];
    const float* conf   = (const float*)d_in[2];
    const float* corpus = (const float*)d_in[3];
    const float* W_pe   = (const float*)d_in[4];
    const float* b_pe   = (const float*)d_in[5];
    const float* W1     = (const float*)d_in[6];
    const float* b1     = (const float*)d_in[7];
    const float* g1     = (const float*)d_in[8];
    const float* be1    = (const float*)d_in[9];
    const float* W2     = (const float*)d_in[10];
    const float* b2     = (const float*)d_in[11];
    const float* g2     = (const float*)d_in[12];
    const float* be2    = (const float*)d_in[13];
    const float* W3     = (const float*)d_in[14];
    const float* b3     = (const float*)d_in[15];
    const float* Wo1    = (const float*)d_in[16];
    const float* bo1    = (const float*)d_in[17];
    const float* Wo2    = (const float*)d_in[18];
    const float* bo2    = (const float*)d_in[19];
    const float* Wt1    = (const float*)d_in[20];
    const float* bt1    = (const float*)d_in[21];
    const float* Wt2    = (const float*)d_in[22];
    const float* bt2    = (const float*)d_in[23];
    const float* Wg1    = (const float*)d_in[24];
    const float* bg1    = (const float*)d_in[25];
    const float* Wg2    = (const float*)d_in[26];
    const float* bg2    = (const float*)d_in[27];

    float* out = (float*)d_out;
    float* ws = (float*)d_ws;

    k_norms<<<125000, 256, 0, stream>>>(corpus, ws + INV_OFF);
    k_pe<<<512, 256, 0, stream>>>(pf, W_pe, b_pe, ws + PET_OFF);
    k_sim_topk<<<dim3(8, NCHUNK), 256, 0, stream>>>(corpus, ws + PET_OFF, ws + INV_OFF,
                                                    ws + CS_OFF, (int*)(ws + CI_OFF));
    k_merge<<<512, 64, 0, stream>>>(ws + CS_OFF, (int*)(ws + CI_OFF),
                                    (int*)(ws + TI_OFF), out);
    k_gather<<<512, 256, 0, stream>>>(conf, corpus, (int*)(ws + TI_OFF), ws + SIN_OFF);
    k_gemm<<<dim3(16, 8), 256, 0, stream>>>(ws + SIN_OFF, W1, b1, ws + H1_OFF, 2176, 1024, 1);
    k_ln<<<512, 256, 0, stream>>>(ws + H1_OFF, g1, be1);
    k_gemm<<<dim3(16, 8), 256, 0, stream>>>(ws + H1_OFF, W2, b2, ws + H2_OFF, 1024, 1024, 1);
    k_ln<<<512, 256, 0, stream>>>(ws + H2_OFF, g2, be2);
    k_gemm<<<dim3(8, 8), 256, 0, stream>>>(ws + H2_OFF, W3, b3, ws + S_OFF, 1024, 512, 0);
    k_scast<<<256, 256, 0, stream>>>(ws + S_OFF, out);
    k_heads<<<512, 256, 0, stream>>>(ws + S_OFF, treat,
                                     Wt1, bt1, Wt2, bt2,
                                     Wo1, bo1, Wo2, bo2,
                                     Wg1, bg1, Wg2, bg2, out);
}